// Round 11
// baseline (1764.968 us; speedup 1.0000x reference)
//
#include <hip/hip_runtime.h>

// Problem constants
constexpr int D  = 128;
constexpr int M  = 8192;
constexpr int L  = 5;
constexpr int K  = 8;
constexpr int KL = 4;
constexpr int G  = 4096;

constexpr int TB   = 64;            // bucket pad granularity
constexpr int PADL = M + K * TB;    // 8704
constexpr int PADG = G + KL * TB;   // 4352

typedef short bf16x8 __attribute__((ext_vector_type(8)));
typedef float f32x4  __attribute__((ext_vector_type(4)));

__device__ __forceinline__ unsigned short f2bf(float x) {
  union { float f; unsigned int u; } c; c.f = x;
  unsigned int u = c.u + 0x7FFF + ((c.u >> 16) & 1);   // RNE
  return (unsigned short)(u >> 16);
}
__device__ __forceinline__ float bf2f(unsigned short h) {
  union { unsigned int u; float f; } c; c.u = ((unsigned int)h) << 16;
  return c.f;
}

// Bijective XCD-chunking swizzle (m204).
__device__ __forceinline__ int xcd_swizzle(int b, int n) {
  int q = n >> 3, r = n & 7, xcd = b & 7, off = b >> 3;
  return (xcd < r ? xcd * (q + 1) : r * (q + 1) + (xcd - r) * q) + off;
}

// All pointers bundled.
struct P {
  const int *leaf_ids, *left_idx, *right_idx, *nf_fid, *gt_left, *gt_right, *lf_fid;
  const float *emb, *W1, *b1, *W2, *b2, *W3, *b3, *Wl1, *bl1, *Wl2, *bl2;
  float* out;
  short *hsA, *hsB, *a1s, *a2s, *B1T, *B2T, *B3T, *BL1T, *BL2T;
  int* orders;
};

// ---------------------------------------------------------------------------
__device__ __forceinline__ void leaf_unit(int u, const P& p) {
  int idx = u * 256 + threadIdx.x;               // over M*128
  int n = idx >> 7, d = idx & 127;
  float w = p.emb[(size_t)p.leaf_ids[n] * D + d];
  unsigned short hh = f2bf(w);
  p.hsA[n * 256 + d]       = (short)hh;
  p.hsA[n * 256 + 128 + d] = (short)f2bf(w - bf2f(hh));
}

// Weight prep via 64x64 LDS transpose tile (both sides coalesced).
__device__ void prep_tile(int b, const P& p, float (*T)[65]) {
  const float* W; short* BT; int KD, F;
  if      (b < 256) { W = p.W1;  BT = p.B1T;  KD = 256; F = 512; }
  else if (b < 512) { W = p.W2;  BT = p.B2T;  KD = 512; F = 256; b -= 256; }
  else if (b < 576) { W = p.W3;  BT = p.B3T;  KD = 256; F = 128; b -= 512; }
  else if (b < 704) { W = p.Wl1; BT = p.BL1T; KD = 256; F = 512; b -= 576; }
  else              { W = p.Wl2; BT = p.BL2T; KD = 512; F = 128; b -= 704; }
  const int ntd = KD >> 6, ntf = F >> 6;
  const int k  = b / (ntd * ntf), rem = b % (ntd * ntf);
  const int d0 = (rem / ntf) << 6, f0 = (rem % ntf) << 6;
  const int tid = threadIdx.x, ln = tid & 63, w4 = tid >> 6;
  #pragma unroll
  for (int i = 0; i < 16; ++i) {                 // read rows d, coalesced over f
    int d = w4 * 16 + i;
    T[ln][d] = W[((size_t)k * KD + d0 + d) * F + f0 + ln];
  }
  __syncthreads();
  #pragma unroll
  for (int i = 0; i < 16; ++i) {                 // write rows f, coalesced over d
    int f = w4 * 16 + i;
    float w = T[f][ln];
    unsigned short hi = f2bf(w);
    unsigned short lo = f2bf(w - bf2f(hi));
    size_t base = ((size_t)k * F + f0 + f) * (2 * KD) + d0;
    BT[base + ln]      = (short)hi;
    BT[base + KD + ln] = (short)lo;
  }
}

// Bucket node indices by fid, padded to 64; pad = -1.
__device__ void bucket_body(int b, const P& p, int* cnt, int* cur) {
  const int* fid; int N, Kf, cap; int* outp;
  if (b < L) { fid = p.nf_fid + b * M; N = M; Kf = K;  cap = PADL; outp = p.orders + b * PADL; }
  else       { fid = p.lf_fid;         N = G; Kf = KL; cap = PADG; outp = p.orders + L * PADL; }
  int tid = threadIdx.x;
  if (tid < Kf) cnt[tid] = 0;
  __syncthreads();
  for (int i = tid; i < N; i += 256) atomicAdd(&cnt[fid[i]], 1);
  __syncthreads();
  if (tid == 0) {
    int off = 0;
    for (int k = 0; k < Kf; ++k) { cur[k] = off; off += ((cnt[k] + TB - 1) / TB) * TB; }
  }
  __syncthreads();
  for (int i = tid; i < cap; i += 256) outp[i] = -1;
  __syncthreads();
  for (int i = tid; i < N; i += 256) {
    int kk = fid[i];
    int pos = atomicAdd(&cur[kk], 1);
    outp[pos] = i;
  }
}

// ---------------------------------------------------------------------------
// Setup kernel: leaf gather + weight prep + bucketing (one dispatch).
__global__ __launch_bounds__(256) void setup_k(P p) {
  __shared__ float T[64][65];
  __shared__ int cnt[8], cur[8];
  int b = blockIdx.x;
  if (b < 4096)      leaf_unit(b, p);
  else if (b < 4864) prep_tile(b - 4096, p, T);
  else               bucket_body(b - 4864, p, cnt, cur);
}

// ---------------------------------------------------------------------------
// One GEMM phase inside a 512-thread (8-wave) block, 32-row tile.
// NCT = NN/128 column-tiles processed CONCURRENTLY by wave-groups:
//   NCT=4: 4 groups x 2 waves   (G1/LG1, NN=512)
//   NCT=2: 2 groups x 4 waves   (G2,    NN=256)
//   NCT=1: 1 group  x 8 waves   (G3/LG2, NN=128)
// Each group double-buffers its own B panel in its Bs region; A (32 rows,
// shared by all groups) staged by the first 256 threads. Same K-chunk order,
// same MFMA accumulation chain per output element as the proven r2 tile ->
// bit-identical numerics. All barriers are block-uniform.
// Split-bf16 logical K' = 3*KH: A segs {hi,lo,hi}, B segs {hi,hi,lo}.
// EPI=0: relu+split bf16 -> Aout rows. EPI=1: fp32 scatter to outp[node].
// EPI=2: split bf16 scatter to Aout[node] (hs rows).
template<int KH, int NN, int EPI, int FUSED>
__device__ void gemm_phase(
    int row0,
    const short* __restrict__ A, const short* __restrict__ hsrc,
    const short* __restrict__ BT, const float* __restrict__ bias,
    short* __restrict__ Aout, float* __restrict__ outp, int kfn,
    const int* nodesS, const int* liS, const int* riS,
    short* As, short* Bs) {
  constexpr int BK   = 64;
  constexpr int NCH  = 3 * KH / BK;     // 12 or 24 (even)
  constexpr int LDA  = 72;              // 2-way bank alias (free)
  constexpr int ASTR = 32 * LDA;
  constexpr int BSTR = 128 * LDA;
  constexpr int NCT  = NN >> 7;         // 4, 2, 1
  constexpr int WPW  = 8 / NCT;         // waves per ct group
  constexpr int TPG  = 512 / NCT;       // threads per ct group
  constexpr int TPRB = TPG / 128;       // B-staging threads per panel row
  constexpr int SOW  = 64 / TPRB;       // shorts per thread per B row
  constexpr int IPT  = SOW / 8;         // int4 per thread (8/4/2)
  constexpr int RF   = (NCT == 4) ? 2 : 1;
  constexpr int CFN  = (NCT == 1) ? 2 : 4;

  const int tid  = threadIdx.x;
  const int wave = tid >> 6, lane = tid & 63;
  const int l15 = lane & 15, oct = lane >> 4;
  const int g    = wave / WPW;          // ct group
  const int lw   = wave % WPW;
  const int ltid = tid & (TPG - 1);
  const int rowbase = (NCT == 4) ? 0 : ((NCT == 2) ? ((lw >> 1) * 16) : ((lw >> 2) * 16));
  const int colbase = (NCT == 4) ? ((lw & 1) * 64)
                                 : ((NCT == 2) ? ((lw & 1) * 64) : ((lw & 3) * 32));

  const int brow = ltid / TPRB;                 // B panel row [0,128)
  const int boff = (ltid % TPRB) * SOW;         // within-row short offset
  short* BsG = Bs + g * 2 * BSTR;
  const short* Bk = BT + (size_t)kfn * NN * (2 * KH)
                       + (size_t)(g * 128 + brow) * (2 * KH) + boff;

  const int ar = tid >> 3, ag = (tid & 7) * 8;  // A staging (tid<256)

  __syncthreads();                              // LDS reuse guard (prev phase)

  f32x4 acc[RF][CFN];
  #pragma unroll
  for (int i = 0; i < RF; ++i)
    #pragma unroll
    for (int j = 0; j < CFN; ++j) acc[i][j] = (f32x4)0.f;

  auto loadB = [&](int c, int4* t) {
    int ko = c * BK;
    int pb = (ko < KH) ? ko : ko - KH;          // B segs {hi,hi,lo}
    const int4* p = (const int4*)(Bk + pb);
    #pragma unroll
    for (int i = 0; i < IPT; ++i) t[i] = p[i];
  };
  auto storeB = [&](int b, const int4* t) {
    int4* d = (int4*)&BsG[b * BSTR + brow * LDA + boff];
    #pragma unroll
    for (int i = 0; i < IPT; ++i) d[i] = t[i];
  };
  auto loadA = [&](int c, int4& r) {
    if (tid < 256) {
      int ko = c * BK, seg = ko / KH, wi = ko % KH;
      int pa = ((seg == 1) ? KH : 0) + wi + ag; // A segs {hi,lo,hi}
      if (FUSED) {
        int s4 = pa >> 7;                       // 0:hi_l 1:hi_r 2:lo_l 3:lo_r
        int node = (s4 & 1) ? riS[ar] : liS[ar];
        if (nodesS[ar] >= 0)
          r = *(const int4*)(hsrc + (size_t)node * 256 + ((s4 >> 1) << 7) + (pa & 127));
        else
          r = make_int4(0, 0, 0, 0);
      } else {
        r = *(const int4*)(A + (size_t)(row0 + ar) * (2 * KH) + pa);
      }
    }
  };
  auto storeA = [&](int b, const int4& r) {
    if (tid < 256) *(int4*)&As[b * ASTR + ar * LDA + ag] = r;
  };
  auto compute = [&](int b) {
    __builtin_amdgcn_s_setprio(1);
    #pragma unroll
    for (int s = 0; s < 2; ++s) {
      const int ko = s * 32 + oct * 8;
      bf16x8 afr[RF];
      #pragma unroll
      for (int rf = 0; rf < RF; ++rf)
        afr[rf] = *(const bf16x8*)&As[b * ASTR + (rowbase + rf * 16 + l15) * LDA + ko];
      #pragma unroll
      for (int cf = 0; cf < CFN; ++cf) {
        bf16x8 bb = *(const bf16x8*)&BsG[b * BSTR + (colbase + cf * 16 + l15) * LDA + ko];
        #pragma unroll
        for (int rf = 0; rf < RF; ++rf)
          acc[rf][cf] = __builtin_amdgcn_mfma_f32_16x16x32_bf16(afr[rf], bb, acc[rf][cf], 0, 0, 0);
      }
    }
    __builtin_amdgcn_s_setprio(0);
  };

  // ---- main loop (r2 structure): dbuf LDS, 2 reg sets, 1 barrier/chunk
  int4 a0, a1, tb0[IPT], tb1[IPT];
  loadA(0, a0); loadB(0, tb0);
  loadA(1, a1); loadB(1, tb1);
  storeA(0, a0); storeB(0, tb0);
  __syncthreads();
  for (int c = 0; c < NCH; c += 2) {
    storeA(1, a1); storeB(1, tb1);              // chunk c+1 -> buf1
    if (c + 2 < NCH) { loadA(c + 2, a0); loadB(c + 2, tb0); }
    compute(0);                                 // chunk c from buf0
    __syncthreads();
    if (c + 2 < NCH) { storeA(0, a0); storeB(0, tb0); }
    if (c + 3 < NCH) { loadA(c + 3, a1); loadB(c + 3, tb1); }
    compute(1);                                 // chunk c+1 from buf1
    __syncthreads();
  }

  // ---- Epilogue
  if (EPI == 0) {
    short* Ls = BsG;                            // group-local 32x128 shorts
    #pragma unroll
    for (int part = 0; part < 2; ++part) {
      __syncthreads();
      #pragma unroll
      for (int rf = 0; rf < RF; ++rf)
        #pragma unroll
        for (int cf = 0; cf < CFN; ++cf) {
          int colL = colbase + cf * 16 + l15;
          float bv = bias[kfn * NN + g * 128 + colL];
          #pragma unroll
          for (int j = 0; j < 4; ++j) {
            int row = rowbase + rf * 16 + oct * 4 + j;
            float v = fmaxf(acc[rf][cf][j] + bv, 0.f);
            unsigned short hh = f2bf(v);
            unsigned short val = (part == 0) ? hh : f2bf(v - bf2f(hh));
            Ls[row * 128 + colL] = (short)val;
          }
        }
      __syncthreads();
      constexpr int IPTE = 512 / TPG;           // int4 per thread (4 or 2)
      #pragma unroll
      for (int q = 0; q < IPTE; ++q) {
        int idx = ltid * IPTE + q;              // [0,512): 32 rows x 16 int4
        int row = idx >> 4, soff = (idx & 15) * 8;
        *(int4*)&Aout[(size_t)(row0 + row) * (2 * NN) + part * NN + g * 128 + soff] =
            *(const int4*)&Ls[row * 128 + soff];
      }
    }
  } else if (EPI == 1) {                        // NCT==1: fp32 scatter
    float* Lf = (float*)Bs;                     // 32x128 floats
    #pragma unroll
    for (int cf = 0; cf < CFN; ++cf) {
      int colG = colbase + cf * 16 + l15;
      float bv = bias[kfn * 128 + colG];
      #pragma unroll
      for (int j = 0; j < 4; ++j) {
        int row = rowbase + oct * 4 + j;
        Lf[row * 128 + colG] = acc[0][cf][j] + bv;
      }
    }
    __syncthreads();
    #pragma unroll
    for (int q = 0; q < 2; ++q) {
      int idx = tid * 2 + q;                    // [0,1024): 32 rows x 32 f4
      int row = idx >> 5, foff = (idx & 31) * 4;
      int node = nodesS[row];
      if (node >= 0)
        *(float4*)&outp[(size_t)node * 128 + foff] =
            *(const float4*)&Lf[row * 128 + foff];
    }
  } else {                                      // EPI==2, NCT==1: hs scatter
    short* Ls = Bs;                             // 32x256 shorts
    #pragma unroll
    for (int cf = 0; cf < CFN; ++cf) {
      int colL = colbase + cf * 16 + l15;
      float bv = bias[kfn * 128 + colL];
      #pragma unroll
      for (int j = 0; j < 4; ++j) {
        int row = rowbase + oct * 4 + j;
        float v = acc[0][cf][j] + bv;
        unsigned short hh = f2bf(v);
        Ls[row * 256 + colL]       = (short)hh;
        Ls[row * 256 + 128 + colL] = (short)f2bf(v - bf2f(hh));
      }
    }
    __syncthreads();
    #pragma unroll
    for (int q = 0; q < 2; ++q) {
      int idx = tid * 2 + q;                    // [0,1024): 32 rows x 32 int4
      int row = idx >> 5, soff = (idx & 31) * 8;
      int node = nodesS[row];
      if (node >= 0)
        *(int4*)&Aout[(size_t)node * 256 + soff] =
            *(const int4*)&Ls[row * 256 + soff];
    }
  }
}

// ---------------------------------------------------------------------------
// Fused level, 512-thread blocks, ct-parallel wave groups. Row-local phase
// chain (proven r10); serial depth 48 chunks (vs r10's 108).
template<bool LOGIC>
__global__ __launch_bounds__(512, 1) void level512(
    P p, const short* hin, short* hout, int lvl) {
  __shared__ __align__(16) short As[2 * 32 * 72];      //   9.2 KB
  __shared__ __align__(16) short Bs[8 * 128 * 72];     // 147.5 KB
  __shared__ int nodesS[32], liS[32], riS[32];

  const int bx   = xcd_swizzle(blockIdx.x, gridDim.x);
  const int row0 = bx * 32;
  const int tid  = threadIdx.x;

  const int* ord = LOGIC ? (p.orders + L * PADL) : (p.orders + lvl * PADL);
  const int* fl  = LOGIC ? p.lf_fid   : (p.nf_fid + lvl * M);
  const int* gl  = LOGIC ? p.gt_left  : (p.left_idx + lvl * M);
  const int* gr  = LOGIC ? p.gt_right : (p.right_idx + lvl * M);

  if (tid < 32) {
    int node = ord[row0 + tid];
    nodesS[tid] = node;
    liS[tid] = node >= 0 ? gl[node] : 0;
    riS[tid] = node >= 0 ? gr[node] : 0;
  }
  __syncthreads();
  if (nodesS[0] < 0) return;                    // padded tile (block-uniform)
  const int kfn = fl[nodesS[0]];

  if (!LOGIC) {
    gemm_phase<256, 512, 0, 1>(row0, nullptr, hin, p.B1T, p.b1,
        p.a1s, nullptr, kfn, nodesS, liS, riS, As, Bs);
    gemm_phase<512, 256, 0, 0>(row0, p.a1s, nullptr, p.B2T, p.b2,
        p.a2s, nullptr, kfn, nodesS, liS, riS, As, Bs);
    gemm_phase<256, 128, 2, 0>(row0, p.a2s, nullptr, p.B3T, p.b3,
        hout, nullptr, kfn, nodesS, liS, riS, As, Bs);
  } else {
    gemm_phase<256, 512, 0, 1>(row0, nullptr, hin, p.BL1T, p.bl1,
        p.a1s, nullptr, kfn, nodesS, liS, riS, As, Bs);
    gemm_phase<512, 128, 1, 0>(row0, p.a1s, nullptr, p.BL2T, p.bl2,
        nullptr, p.out, kfn, nodesS, liS, riS, As, Bs);
  }
}

// ---------------------------------------------------------------------------
extern "C" void kernel_launch(void* const* d_in, const int* in_sizes, int n_in,
                              void* d_out, int out_size, void* d_ws, size_t ws_size,
                              hipStream_t stream) {
  // workspace layout (~54 MB)
  const size_t SZ_H    = (size_t)M * 256 * 2;          // split-bf16 h rows
  const size_t SZ_A1   = (size_t)PADL * 1024 * 2;
  const size_t SZ_A2   = (size_t)PADL * 512 * 2;
  const size_t SZ_B1T  = (size_t)8 * 512 * 512 * 2;
  const size_t SZ_B2T  = (size_t)8 * 256 * 1024 * 2;
  const size_t SZ_B3T  = (size_t)8 * 128 * 512 * 2;
  const size_t SZ_BL1T = (size_t)4 * 512 * 512 * 2;
  const size_t SZ_BL2T = (size_t)4 * 128 * 1024 * 2;

  char* q = (char*)d_ws;
  short* hsA  = (short*)q;  q += SZ_H;
  short* hsB  = (short*)q;  q += SZ_H;
  short* a1s  = (short*)q;  q += SZ_A1;
  short* a2s  = (short*)q;  q += SZ_A2;
  short* B1T  = (short*)q;  q += SZ_B1T;
  short* B2T  = (short*)q;  q += SZ_B2T;
  short* B3T  = (short*)q;  q += SZ_B3T;
  short* BL1T = (short*)q;  q += SZ_BL1T;
  short* BL2T = (short*)q;  q += SZ_BL2T;
  int*   orders = (int*)q;

  P prm;
  prm.leaf_ids  = (const int*)d_in[0];
  prm.left_idx  = (const int*)d_in[1];
  prm.right_idx = (const int*)d_in[2];
  prm.nf_fid    = (const int*)d_in[3];
  prm.gt_left   = (const int*)d_in[4];
  prm.gt_right  = (const int*)d_in[5];
  prm.lf_fid    = (const int*)d_in[6];
  prm.emb       = (const float*)d_in[7];
  prm.W1 = (const float*)d_in[8];  prm.b1 = (const float*)d_in[9];
  prm.W2 = (const float*)d_in[10]; prm.b2 = (const float*)d_in[11];
  prm.W3 = (const float*)d_in[12]; prm.b3 = (const float*)d_in[13];
  prm.Wl1 = (const float*)d_in[14]; prm.bl1 = (const float*)d_in[15];
  prm.Wl2 = (const float*)d_in[16]; prm.bl2 = (const float*)d_in[17];
  prm.out = (float*)d_out;
  prm.hsA = hsA; prm.hsB = hsB; prm.a1s = a1s; prm.a2s = a2s;
  prm.B1T = B1T; prm.B2T = B2T; prm.B3T = B3T; prm.BL1T = BL1T; prm.BL2T = BL2T;
  prm.orders = orders;

  setup_k<<<4870, 256, 0, stream>>>(prm);       // leaf + prep + bucket

  short* hin = hsA;
  short* hout = hsB;
  for (int l = 0; l < L; ++l) {                 // 5 fused level dispatches
    level512<false><<<PADL / 32, 512, 0, stream>>>(prm, hin, hout, l);
    short* t = hin; hin = hout; hout = t;
  }
  level512<true><<<PADG / 32, 512, 0, stream>>>(prm, hin, nullptr, 0);
}